// Round 8
// baseline (3254.248 us; speedup 1.0000x reference)
//
#include <hip/hip_runtime.h>
#include <hip/hip_bf16.h>
#include <cstdint>

#define NBATCH 512
#define NDIM   2048
#define NHEADS 16
#define NCPH   128

typedef __bf16 bf16x8 __attribute__((ext_vector_type(8)));
typedef float  f32x4  __attribute__((ext_vector_type(4)));

__device__ __forceinline__ unsigned short f2bf(float f) {
    uint32_t u = __builtin_bit_cast(uint32_t, f);
    u += 0x7FFFu + ((u >> 16) & 1u);   // round-to-nearest-even
    return (unsigned short)(u >> 16);
}

// ---------------- bf16-MFMA GEMM, deep-pipelined reg staging -----------
// MEASUREMENT BUILD: REPS in-kernel repetitions (deterministic; same
// output rewritten) to make this dispatch visible in rocprof top-5.
template<int BM, int BN, int BK, bool A_BF16, bool BNP, int REPS>
__global__ __launch_bounds__(256) void gemm_deep(
    const unsigned short* __restrict__ Abf, const float* __restrict__ Af,
    const float* __restrict__ Bf, float* __restrict__ C,
    const float* __restrict__ bias, float* __restrict__ bnpart,
    int M, int N, int K)
{
    constexpr int WM = BM / 2, WN = BN / 2;
    constexpr int MI = WM / 16, NI = WN / 16;
    constexpr int CPR = BK / 8;
    constexpr int RNA = (BM * BK) / 2048;
    constexpr int RNB = (BN * BK) / 2048;

    __shared__ unsigned short As[2][BM * BK];
    __shared__ unsigned short Bs[2][BN * BK];

    const int tid  = threadIdx.x;
    const int lane = tid & 63;
    const int wid  = tid >> 6;
    const int wr   = wid >> 1;
    const int wc   = wid & 1;
    const int m0   = blockIdx.y * BM;
    const int n0   = blockIdx.x * BN;
    const int fr   = lane & 15;
    const int kq   = lane >> 4;

    f32x4 acc[MI][NI];

    float4 fA0[A_BF16 ? 1 : RNA][2], fA1[A_BF16 ? 1 : RNA][2];
    bf16x8 hA0[A_BF16 ? RNA : 1],    hA1[A_BF16 ? RNA : 1];
    float4 fB0[RNB][2], fB1[RNB][2];

    auto loadA = [&](auto& fa, auto& ha, int k0) {
        if constexpr (A_BF16) {
#pragma unroll
            for (int r = 0; r < RNA; r++) {
                const int e = r * 2048 + tid * 8;
                const int row = e / BK, cb = e % BK;
                ha[r] = *(const bf16x8*)(Abf + (size_t)(m0 + row) * K + k0 + cb);
            }
        } else {
#pragma unroll
            for (int r = 0; r < RNA; r++) {
                const int idx = r * 256 + tid;
                const int row = idx / CPR, cc = idx % CPR;
                const float4* g = (const float4*)(Af + (size_t)(m0 + row) * K
                                                  + k0 + cc * 8);
                fa[r][0] = g[0];
                fa[r][1] = g[1];
            }
        }
    };
    auto loadB = [&](auto& fb, int k0) {
#pragma unroll
        for (int r = 0; r < RNB; r++) {
            const int idx = r * 256 + tid;
            const int row = idx / CPR, cc = idx % CPR;
            const float4* g = (const float4*)(Bf + (size_t)(n0 + row) * K
                                              + k0 + cc * 8);
            fb[r][0] = g[0];
            fb[r][1] = g[1];
        }
    };
    auto writeA = [&](int bs, auto& fa, auto& ha) {
        if constexpr (A_BF16) {
#pragma unroll
            for (int r = 0; r < RNA; r++) {
                const int e = r * 2048 + tid * 8;
                const int row = e / BK, cc = (e % BK) >> 3;
                *(bf16x8*)&As[bs][row * BK + ((cc ^ (row & 7)) << 3)] = ha[r];
            }
        } else {
#pragma unroll
            for (int r = 0; r < RNA; r++) {
                const int idx = r * 256 + tid;
                const int row = idx / CPR, cc = idx % CPR;
                bf16x8 v;
                v[0] = (__bf16)fa[r][0].x; v[1] = (__bf16)fa[r][0].y;
                v[2] = (__bf16)fa[r][0].z; v[3] = (__bf16)fa[r][0].w;
                v[4] = (__bf16)fa[r][1].x; v[5] = (__bf16)fa[r][1].y;
                v[6] = (__bf16)fa[r][1].z; v[7] = (__bf16)fa[r][1].w;
                *(bf16x8*)&As[bs][row * BK + ((cc ^ (row & 7)) << 3)] = v;
            }
        }
    };
    auto writeB = [&](int bs, auto& fb) {
#pragma unroll
        for (int r = 0; r < RNB; r++) {
            const int idx = r * 256 + tid;
            const int row = idx / CPR, cc = idx % CPR;
            bf16x8 v;
            v[0] = (__bf16)fb[r][0].x; v[1] = (__bf16)fb[r][0].y;
            v[2] = (__bf16)fb[r][0].z; v[3] = (__bf16)fb[r][0].w;
            v[4] = (__bf16)fb[r][1].x; v[5] = (__bf16)fb[r][1].y;
            v[6] = (__bf16)fb[r][1].z; v[7] = (__bf16)fb[r][1].w;
            *(bf16x8*)&Bs[bs][row * BK + ((cc ^ (row & 7)) << 3)] = v;
        }
    };
    auto compute = [&](int bs) {
#pragma unroll
        for (int kh = 0; kh < BK / 32; kh++) {
            const int kchunk = kh * 4 + kq;
            bf16x8 af[MI], bfv[NI];
#pragma unroll
            for (int i = 0; i < MI; i++) {
                const int row = wr * WM + i * 16 + fr;
                af[i] = *(const bf16x8*)&As[bs][row * BK
                        + ((kchunk ^ (row & 7)) << 3)];
            }
#pragma unroll
            for (int j = 0; j < NI; j++) {
                const int row = wc * WN + j * 16 + fr;
                bfv[j] = *(const bf16x8*)&Bs[bs][row * BK
                         + ((kchunk ^ (row & 7)) << 3)];
            }
#pragma unroll
            for (int i = 0; i < MI; i++)
#pragma unroll
                for (int j = 0; j < NI; j++)
                    acc[i][j] = __builtin_amdgcn_mfma_f32_16x16x32_bf16(
                        af[i], bfv[j], acc[i][j], 0, 0, 0);
        }
    };
    auto barrier = [&]() {
        asm volatile("s_waitcnt lgkmcnt(0)" ::: "memory");
        __builtin_amdgcn_s_barrier();
        __builtin_amdgcn_sched_barrier(0);
    };

    for (int rep = 0; rep < REPS; rep++) {
        __syncthreads();
#pragma unroll
        for (int i = 0; i < MI; i++)
#pragma unroll
            for (int j = 0; j < NI; j++)
                acc[i][j] = f32x4{0.f, 0.f, 0.f, 0.f};

        loadA(fA0, hA0, 0);
        loadB(fB0, 0);
        loadA(fA1, hA1, BK);
        loadB(fB1, BK);
        writeA(0, fA0, hA0);
        writeB(0, fB0);
        barrier();

        const int NT = K / BK;
        for (int t = 0; t < NT; t += 2) {
            if (t + 2 < NT) { loadA(fA0, hA0, (t + 2) * BK); loadB(fB0, (t + 2) * BK); }
            compute(0);
            writeA(1, fA1, hA1);
            writeB(1, fB1);
            barrier();
            if (t + 3 < NT) { loadA(fA1, hA1, (t + 3) * BK); loadB(fB1, (t + 3) * BK); }
            compute(1);
            if (t + 2 < NT) {
                writeA(0, fA0, hA0);
                writeB(0, fB0);
                barrier();
            }
        }

        const int row0 = m0 + wr * WM + (kq << 2);
        const int col0 = n0 + wc * WN + fr;
#pragma unroll
        for (int j = 0; j < NI; j++) {
            const int cc = col0 + j * 16;
            const float badd = bias ? bias[cc] : 0.0f;
#pragma unroll
            for (int i = 0; i < MI; i++)
#pragma unroll
                for (int r = 0; r < 4; r++)
                    C[(size_t)(row0 + i * 16 + r) * N + cc] = acc[i][j][r] + badd;
        }

        if (BNP && n0 >= NDIM) {
            float s = 0.f, ss = 0.f;
#pragma unroll
            for (int i = 0; i < MI; i++)
#pragma unroll
                for (int j = 0; j < NI; j++)
#pragma unroll
                    for (int r = 0; r < 4; r++) {
                        const float v = acc[i][j][r];
                        s += v;
                        ss = fmaf(v, v, ss);
                    }
#pragma unroll
            for (int off = 32; off; off >>= 1) {
                s  += __shfl_down(s, off);
                ss += __shfl_down(ss, off);
            }
            __shared__ float rs[4], rss[4];
            if (lane == 0) { rs[wid] = s; rss[wid] = ss; }
            __syncthreads();
            if (tid == 0)
                ((float2*)bnpart)[((n0 - NDIM) >> 6) * 8 + (m0 >> 6)] =
                    make_float2(rs[0] + rs[1] + rs[2] + rs[3],
                                rss[0] + rss[1] + rss[2] + rss[3]);
        }
    }
}

// ---------------- fused BN-final + outer-product + softmax + PV --------
// MEASUREMENT BUILD: REPS in-kernel repetitions.
template<int REPS>
__global__ __launch_bounds__(256) void attn_k(
    const float* __restrict__ qv, const float* __restrict__ kparam,
    const float* __restrict__ bias, const float* __restrict__ temperature,
    const float* __restrict__ bnpart, const float* __restrict__ gamma,
    const float* __restrict__ beta, unsigned short* __restrict__ aout)
{
    const int bh2 = blockIdx.x;
    const int bh  = bh2 >> 1, rh = bh2 & 1;
    const int b   = bh >> 4,  h  = bh & 15;
    const int tid = threadIdx.x;

    __shared__ float ks[NCPH], vsr[NCPH], s2sh[2];

    for (int rep = 0; rep < REPS; rep++) {
        __syncthreads();
        if (tid < 32)
            ((float4*)ks)[tid] =
                ((const float4*)(kparam + (size_t)b * NDIM + h * NCPH))[tid];
        else if (tid < 64)
            ((float4*)vsr)[tid - 32] =
                ((const float4*)(qv + (size_t)b * (2 * NDIM) + NDIM + h * NCPH))[tid - 32];

        if (tid < 16) {
            float2 p = ((const float2*)bnpart)[(h * 2 + (tid >> 3)) * 8 + (tid & 7)];
            float s = p.x, ss = p.y;
#pragma unroll
            for (int off = 8; off; off >>= 1) {
                s  += __shfl_xor(s, off);
                ss += __shfl_xor(ss, off);
            }
            if (tid == 0) {
                const float inv = 1.0f / (NBATCH * NCPH);
                float mean = s * inv;
                float var  = ss * inv - mean * mean;
                float scl  = gamma[h] * rsqrtf(var + 1e-5f);
                s2sh[0] = scl;
                s2sh[1] = beta[h] - mean * scl;
            }
        }

        const int c  = rh * 64 + (tid >> 2);
        const int q4 = tid & 3;
        const float qc   = qv[(size_t)b * (2 * NDIM) + h * NCPH + c];
        const float temp = temperature[h];

        const float4* bp = (const float4*)(bias + ((size_t)bh << 14)
                                           + (size_t)c * NCPH + q4 * 32);
        float4 l4[8];
#pragma unroll
        for (int j = 0; j < 8; j++) l4[j] = bp[j];

        __syncthreads();
        const float scl = s2sh[0], shf = s2sh[1];
        const float4* kk4 = (const float4*)(ks  + q4 * 32);
        const float4* vv4 = (const float4*)(vsr + q4 * 32);

        float s0 = 0.f, s1 = 0.f, o0 = 0.f, o1 = 0.f;
#pragma unroll
        for (int j = 0; j < 8; j++) {
            const float4 bb = l4[j];
            const float4 kx = kk4[j];
            const float4 vx = vv4[j];
            float px = __expf(fmaf(qc, kx.x, bb.x) * temp);
            float py = __expf(fmaf(qc, kx.y, bb.y) * temp);
            float pz = __expf(fmaf(qc, kx.z, bb.z) * temp);
            float pw = __expf(fmaf(qc, kx.w, bb.w) * temp);
            s0 += px; s1 += py; s0 += pz; s1 += pw;
            o0 = fmaf(px, vx.x, o0);
            o1 = fmaf(py, vx.y, o1);
            o0 = fmaf(pz, vx.z, o0);
            o1 = fmaf(pw, vx.w, o1);
        }
        float s = s0 + s1, o = o0 + o1;
        s += __shfl_xor(s, 1);
        o += __shfl_xor(o, 1);
        s += __shfl_xor(s, 2);
        o += __shfl_xor(o, 2);

        if (q4 == 0)
            aout[(size_t)b * NDIM + h * NCPH + c] = f2bf(fmaf(scl, o / s, shf));
    }
}

// ------------------------------ launch ---------------------------------
extern "C" void kernel_launch(void* const* d_in, const int* in_sizes, int n_in,
                              void* d_out, int out_size, void* d_ws, size_t ws_size,
                              hipStream_t stream)
{
    const float* x      = (const float*)d_in[0];
    const float* Wqv    = (const float*)d_in[1];
    const float* temp   = (const float*)d_in[2];
    const float* kparam = (const float*)d_in[3];
    const float* bias   = (const float*)d_in[4];
    const float* gamma  = (const float*)d_in[5];
    const float* beta   = (const float*)d_in[6];
    const float* Wout   = (const float*)d_in[7];
    const float* bout   = (const float*)d_in[8];
    float* out = (float*)d_out;

    char* ws = (char*)d_ws;
    float*          qv     = (float*)(ws);                      // 8 MiB
    unsigned short* ao_bf  = (unsigned short*)(ws + 8388608);   // 2 MiB
    float*          bnpart = (float*)(ws + 10485760);           // 2 KiB

    // MEASUREMENT ROUND: REPS loops make each kernel a >400us dispatch so
    // rocprof top-5 shows per-kernel counters. per-kernel dur = dur/REPS.
    gemm_deep<64, 64, 64, false, true, 48><<<dim3(64, 8), 256, 0, stream>>>(
        nullptr, x, Wqv, qv, nullptr, bnpart, NBATCH, 2 * NDIM, NDIM);

    attn_k<6><<<2 * NBATCH * NHEADS, 256, 0, stream>>>(
        qv, kparam, bias, temp, bnpart, gamma, beta, ao_bf);

    gemm_deep<64, 32, 64, true, false, 64><<<dim3(64, 8), 256, 0, stream>>>(
        ao_bf, nullptr, Wout, out, bout, nullptr, NBATCH, NDIM, NDIM);
}

// Round 9
// 188.371 us; speedup vs baseline: 17.2757x; 17.2757x over previous
//
#include <hip/hip_runtime.h>
#include <hip/hip_bf16.h>
#include <cstdint>

#define NBATCH 512
#define NDIM   2048
#define NHEADS 16
#define NCPH   128

typedef __bf16 bf16x8 __attribute__((ext_vector_type(8)));
typedef float  f32x4  __attribute__((ext_vector_type(4)));

__device__ __forceinline__ unsigned short f2bf(float f) {
    uint32_t u = __builtin_bit_cast(uint32_t, f);
    u += 0x7FFFu + ((u >> 16) & 1u);   // round-to-nearest-even
    return (unsigned short)(u >> 16);
}

// ---------------- bf16-MFMA split-K GEMM, reg-staged ------------------
// Cpart[z][m][n] = sum_{k in slice z} A[m,k]*B[n,k]
// BK=32: small staging (RNA=RNB=1 round) -> ~116 VGPR; launch_bounds
// (256,4) + 16KB LDS => 4 blocks/CU = 16 waves/CU in 4 independent
// barrier groups (the latency-hiding lever r8's counters demanded).
// 2-ahead register prefetch, lgkm-only barrier drain.
template<int BM, int BN, int BK, bool A_BF16>
__global__ __launch_bounds__(256, 4) void gemm_sk(
    const unsigned short* __restrict__ Abf, const float* __restrict__ Af,
    const float* __restrict__ Bf, float* __restrict__ Cpart,
    int M, int N, int K, int KS)
{
    constexpr int WM = BM / 2, WN = BN / 2;
    constexpr int MI = WM / 16, NI = WN / 16;
    constexpr int CPR = BK / 8;

    __shared__ unsigned short As[2][BM * BK];
    __shared__ unsigned short Bs[2][BN * BK];

    const int tid  = threadIdx.x;
    const int lane = tid & 63;
    const int wid  = tid >> 6;
    const int wr   = wid >> 1;
    const int wc   = wid & 1;
    const int m0   = blockIdx.y * BM;
    const int n0   = blockIdx.x * BN;
    const int kbase = blockIdx.z * KS;
    const int fr   = lane & 15;
    const int kq   = lane >> 4;

    f32x4 acc[MI][NI] = {};

    // one staging round per tile (BM*BK == 2048 elems == 256 thr * 8)
    float4 fA0[2], fA1[2], fB0[2], fB1[2];
    bf16x8 hA0, hA1;

    const int arow = tid / CPR, acc8 = tid % CPR;   // A stage coords
    const int brow = tid / CPR, bcc8 = tid % CPR;   // B stage coords

    auto loadA = [&](float4* fa, bf16x8& ha, int k0) {
        if constexpr (A_BF16) {
            ha = *(const bf16x8*)(Abf + (size_t)(m0 + arow) * K + k0 + acc8 * 8);
        } else {
            const float4* g = (const float4*)(Af + (size_t)(m0 + arow) * K
                                              + k0 + acc8 * 8);
            fa[0] = g[0];
            fa[1] = g[1];
        }
    };
    auto loadB = [&](float4* fb, int k0) {
        const float4* g = (const float4*)(Bf + (size_t)(n0 + brow) * K
                                          + k0 + bcc8 * 8);
        fb[0] = g[0];
        fb[1] = g[1];
    };
    auto writeA = [&](int bs, float4* fa, bf16x8& ha) {
        if constexpr (A_BF16) {
            *(bf16x8*)&As[bs][arow * BK + ((acc8 ^ (arow & 3)) << 3)] = ha;
        } else {
            bf16x8 v;
            v[0] = (__bf16)fa[0].x; v[1] = (__bf16)fa[0].y;
            v[2] = (__bf16)fa[0].z; v[3] = (__bf16)fa[0].w;
            v[4] = (__bf16)fa[1].x; v[5] = (__bf16)fa[1].y;
            v[6] = (__bf16)fa[1].z; v[7] = (__bf16)fa[1].w;
            *(bf16x8*)&As[bs][arow * BK + ((acc8 ^ (arow & 3)) << 3)] = v;
        }
    };
    auto writeB = [&](int bs, float4* fb) {
        bf16x8 v;
        v[0] = (__bf16)fb[0].x; v[1] = (__bf16)fb[0].y;
        v[2] = (__bf16)fb[0].z; v[3] = (__bf16)fb[0].w;
        v[4] = (__bf16)fb[1].x; v[5] = (__bf16)fb[1].y;
        v[6] = (__bf16)fb[1].z; v[7] = (__bf16)fb[1].w;
        *(bf16x8*)&Bs[bs][brow * BK + ((bcc8 ^ (brow & 3)) << 3)] = v;
    };
    auto compute = [&](int bs) {
        bf16x8 af[MI], bfv[NI];
#pragma unroll
        for (int i = 0; i < MI; i++) {
            const int row = wr * WM + i * 16 + fr;
            af[i] = *(const bf16x8*)&As[bs][row * BK + ((kq ^ (row & 3)) << 3)];
        }
#pragma unroll
        for (int j = 0; j < NI; j++) {
            const int row = wc * WN + j * 16 + fr;
            bfv[j] = *(const bf16x8*)&Bs[bs][row * BK + ((kq ^ (row & 3)) << 3)];
        }
#pragma unroll
        for (int i = 0; i < MI; i++)
#pragma unroll
            for (int j = 0; j < NI; j++)
                acc[i][j] = __builtin_amdgcn_mfma_f32_16x16x32_bf16(
                    af[i], bfv[j], acc[i][j], 0, 0, 0);
    };
    auto barrier = [&]() {
        asm volatile("s_waitcnt lgkmcnt(0)" ::: "memory");
        __builtin_amdgcn_s_barrier();
        __builtin_amdgcn_sched_barrier(0);
    };

    loadA(fA0, hA0, kbase);
    loadB(fB0, kbase);
    loadA(fA1, hA1, kbase + BK);
    loadB(fB1, kbase + BK);
    writeA(0, fA0, hA0);
    writeB(0, fB0);
    barrier();

    const int NT = KS / BK;   // even
    for (int t = 0; t < NT; t += 2) {
        if (t + 2 < NT) { loadA(fA0, hA0, kbase + (t + 2) * BK);
                          loadB(fB0, kbase + (t + 2) * BK); }
        compute(0);
        writeA(1, fA1, hA1);
        writeB(1, fB1);
        barrier();
        if (t + 3 < NT) { loadA(fA1, hA1, kbase + (t + 3) * BK);
                          loadB(fB1, kbase + (t + 3) * BK); }
        compute(1);
        if (t + 2 < NT) {
            writeA(0, fA0, hA0);
            writeB(0, fB0);
            barrier();
        }
    }

    float* Cp = Cpart + (size_t)blockIdx.z * M * N;
    const int row0 = m0 + wr * WM + (kq << 2);
    const int col0 = n0 + wc * WN + fr;
#pragma unroll
    for (int j = 0; j < NI; j++) {
        const int cc = col0 + j * 16;
#pragma unroll
        for (int i = 0; i < MI; i++)
#pragma unroll
            for (int r = 0; r < 4; r++)
                Cp[(size_t)(row0 + i * 16 + r) * N + cc] = acc[i][j][r];
    }
}

// ---------------- reduce split-K partials -> qv, + per-(b,h) BN sums ---
// one block per row b; thread t owns cols [t*16, t*16+16) of N=4096
__global__ __launch_bounds__(256) void reduce1(
    const float* __restrict__ part, float* __restrict__ qv,
    float* __restrict__ bnpart)
{
    const int b = blockIdx.x, t = threadIdx.x;
    const size_t row = (size_t)b * (2 * NDIM);
    const size_t sks = (size_t)NBATCH * (2 * NDIM);
    float4 acc[4];
#pragma unroll
    for (int f = 0; f < 4; f++) {
        const size_t off = row + t * 16 + f * 4;
        float4 a = *(const float4*)&part[off];
        float4 c = *(const float4*)&part[sks + off];
        acc[f] = make_float4(a.x + c.x, a.y + c.y, a.z + c.z, a.w + c.w);
        *(float4*)&qv[off] = acc[f];
    }
    if (t >= 128) {   // v-half: 8 threads per head
        float s = 0.f, ss = 0.f;
#pragma unroll
        for (int f = 0; f < 4; f++) {
            s  += acc[f].x + acc[f].y + acc[f].z + acc[f].w;
            ss = fmaf(acc[f].x, acc[f].x, fmaf(acc[f].y, acc[f].y,
                 fmaf(acc[f].z, acc[f].z, fmaf(acc[f].w, acc[f].w, ss))));
        }
#pragma unroll
        for (int off = 1; off < 8; off <<= 1) {
            s  += __shfl_xor(s, off);
            ss += __shfl_xor(ss, off);
        }
        if ((t & 7) == 0)
            ((float2*)bnpart)[b * NHEADS + ((t - 128) >> 3)] = make_float2(s, ss);
    }
}

// ---------------- finalize BN: 512x16 partials -> 16 (scale, shift) ----
__global__ __launch_bounds__(256) void bn_final(
    const float* __restrict__ bnpart, const float* __restrict__ gamma,
    const float* __restrict__ beta, float* __restrict__ sc2)
{
    const int t = threadIdx.x;
    const int h = t >> 4, j = t & 15;    // 16 threads per head
    float s = 0.f, ss = 0.f;
#pragma unroll
    for (int i = 0; i < 32; i++) {
        float2 p = ((const float2*)bnpart)[(j + 16 * i) * NHEADS + h];
        s += p.x; ss += p.y;
    }
#pragma unroll
    for (int off = 1; off < 16; off <<= 1) {
        s  += __shfl_xor(s, off);
        ss += __shfl_xor(ss, off);
    }
    if (j == 0) {
        const float inv = 1.0f / (NBATCH * NCPH);
        float mean = s * inv;
        float var  = ss * inv - mean * mean;
        float scl  = gamma[h] * rsqrtf(var + 1e-5f);
        ((float2*)sc2)[h] = make_float2(scl, beta[h] - mean * scl);
    }
}

// ---------------- fused outer-product + bias + softmax + PV ------------
// Single-pass no-max softmax (|logit| <~ 30 << 88). 4 threads per row;
// all 8 bias float4 in flight upfront. block = half a (b,h).
__global__ __launch_bounds__(256) void attn_k(
    const float* __restrict__ qv, const float* __restrict__ kparam,
    const float* __restrict__ bias, const float* __restrict__ temperature,
    const float* __restrict__ sc2, unsigned short* __restrict__ aout)
{
    const int bh2 = blockIdx.x;
    const int bh  = bh2 >> 1, rh = bh2 & 1;
    const int b   = bh >> 4,  h  = bh & 15;
    const int tid = threadIdx.x;

    __shared__ float ks[NCPH], vsr[NCPH];
    if (tid < 32)
        ((float4*)ks)[tid] =
            ((const float4*)(kparam + (size_t)b * NDIM + h * NCPH))[tid];
    else if (tid < 64)
        ((float4*)vsr)[tid - 32] =
            ((const float4*)(qv + (size_t)b * (2 * NDIM) + NDIM + h * NCPH))[tid - 32];

    const int c  = rh * 64 + (tid >> 2);
    const int q4 = tid & 3;
    const float qc   = qv[(size_t)b * (2 * NDIM) + h * NCPH + c];
    const float temp = temperature[h];
    const float2 s2  = ((const float2*)sc2)[h];

    const float4* bp = (const float4*)(bias + ((size_t)bh << 14)
                                       + (size_t)c * NCPH + q4 * 32);
    float4 l4[8];
#pragma unroll
    for (int j = 0; j < 8; j++) l4[j] = bp[j];

    __syncthreads();
    const float4* kk4 = (const float4*)(ks  + q4 * 32);
    const float4* vv4 = (const float4*)(vsr + q4 * 32);

    float s0 = 0.f, s1 = 0.f, o0 = 0.f, o1 = 0.f;
#pragma unroll
    for (int j = 0; j < 8; j++) {
        const float4 bb = l4[j];
        const float4 kx = kk4[j];
        const float4 vx = vv4[j];
        float px = __expf(fmaf(qc, kx.x, bb.x) * temp);
        float py = __expf(fmaf(qc, kx.y, bb.y) * temp);
        float pz = __expf(fmaf(qc, kx.z, bb.z) * temp);
        float pw = __expf(fmaf(qc, kx.w, bb.w) * temp);
        s0 += px; s1 += py; s0 += pz; s1 += pw;
        o0 = fmaf(px, vx.x, o0);
        o1 = fmaf(py, vx.y, o1);
        o0 = fmaf(pz, vx.z, o0);
        o1 = fmaf(pw, vx.w, o1);
    }
    float s = s0 + s1, o = o0 + o1;
    s += __shfl_xor(s, 1);
    o += __shfl_xor(o, 1);
    s += __shfl_xor(s, 2);
    o += __shfl_xor(o, 2);

    if (q4 == 0)
        aout[(size_t)b * NDIM + h * NCPH + c] = f2bf(fmaf(s2.x, o / s, s2.y));
}

// ---------------- reduce split-K partials -> out (+b_out) --------------
__global__ __launch_bounds__(256) void reduce2(
    const float* __restrict__ part, float* __restrict__ outp,
    const float* __restrict__ bout)
{
    const int b = blockIdx.x, t = threadIdx.x;
    const size_t row = (size_t)b * NDIM;
    const size_t sks = (size_t)NBATCH * NDIM;
#pragma unroll
    for (int f = 0; f < 2; f++) {
        const size_t off = row + t * 8 + f * 4;
        const int col = t * 8 + f * 4;
        float4 a = *(const float4*)&part[off];
        float4 c = *(const float4*)&part[sks + off];
        float4 d = *(const float4*)&part[2 * sks + off];
        float4 e = *(const float4*)&part[3 * sks + off];
        float4 bb = *(const float4*)&bout[col];
        float4 r;
        r.x = a.x + c.x + d.x + e.x + bb.x;
        r.y = a.y + c.y + d.y + e.y + bb.y;
        r.z = a.z + c.z + d.z + e.z + bb.z;
        r.w = a.w + c.w + d.w + e.w + bb.w;
        *(float4*)&outp[off] = r;
    }
}

// ------------------------------ launch ---------------------------------
extern "C" void kernel_launch(void* const* d_in, const int* in_sizes, int n_in,
                              void* d_out, int out_size, void* d_ws, size_t ws_size,
                              hipStream_t stream)
{
    const float* x      = (const float*)d_in[0];
    const float* Wqv    = (const float*)d_in[1];
    const float* temp   = (const float*)d_in[2];
    const float* kparam = (const float*)d_in[3];
    const float* bias   = (const float*)d_in[4];
    const float* gamma  = (const float*)d_in[5];
    const float* beta   = (const float*)d_in[6];
    const float* Wout   = (const float*)d_in[7];
    const float* bout   = (const float*)d_in[8];
    float* out = (float*)d_out;

    char* ws = (char*)d_ws;
    float*          qv     = (float*)(ws);                      //  8 MiB
    unsigned short* ao_bf  = (unsigned short*)(ws + 8388608);   //  2 MiB
    float*          part1  = (float*)(ws + 10485760);           // 16 MiB
    float*          part2  = (float*)(ws + 27262976);           // 16 MiB
    float*          bnpart = (float*)(ws + 44040192);           // 64 KiB
    float*          sc2    = (float*)(ws + 44105728);           // 128 B

    // qv partials: M=512, N=4096, K=2048, SK=2 (1024 blocks = 4/CU)
    gemm_sk<64, 64, 32, false><<<dim3(64, 8, 2), 256, 0, stream>>>(
        nullptr, x, Wqv, part1, NBATCH, 2 * NDIM, NDIM, NDIM / 2);

    reduce1<<<NBATCH, 256, 0, stream>>>(part1, qv, bnpart);

    bn_final<<<1, 256, 0, stream>>>(bnpart, gamma, beta, sc2);

    attn_k<<<2 * NBATCH * NHEADS, 256, 0, stream>>>(
        qv, kparam, bias, temp, sc2, ao_bf);

    // out partials: M=512, N=2048, K=2048, SK=4 (1024 blocks = 4/CU)
    gemm_sk<64, 64, 32, true><<<dim3(32, 8, 4), 256, 0, stream>>>(
        ao_bf, nullptr, Wout, part2, NBATCH, NDIM, NDIM, NDIM / 4);

    reduce2<<<NBATCH, 256, 0, stream>>>(part2, out, bout);
}

// Round 10
// 183.618 us; speedup vs baseline: 17.7229x; 1.0259x over previous
//
#include <hip/hip_runtime.h>
#include <hip/hip_bf16.h>
#include <cstdint>

#define NBATCH 512
#define NDIM   2048
#define NHEADS 16
#define NCPH   128

typedef __bf16 bf16x8 __attribute__((ext_vector_type(8)));
typedef float  f32x4  __attribute__((ext_vector_type(4)));

__device__ __forceinline__ unsigned short f2bf(float f) {
    uint32_t u = __builtin_bit_cast(uint32_t, f);
    u += 0x7FFFu + ((u >> 16) & 1u);   // round-to-nearest-even
    return (unsigned short)(u >> 16);
}

__device__ __forceinline__ void gl_lds16(const void* g, void* l) {
    __builtin_amdgcn_global_load_lds(
        (const __attribute__((address_space(1))) void*)g,
        (__attribute__((address_space(3))) void*)l,
        16, 0, 0);
}

// ---------------- bf16-MFMA GEMM with in-kernel f32->bf16 staging -------
// C[m,n] = sum_k A[m,k]*B[n,k] (+bias[n]).  B is always f32 (weights),
// reg-staged (global f32 -> cvt -> swizzled ds_write).  A is either f32
// (x; reg-staged) or bf16 (attn out; global_load_lds w/ pre-swizzled src).
// GRID IS (m-blocks, n-blocks): linear id = mblk + 8*nblk, XCD = id%8 =
// mblk -> each XCD pins ONE A-panel in its L2 (reused by all its blocks)
// while B-panels stream through L3 exactly once.  (r8 counters: the old
// (n,m) grid put 8 A-panels x 8 B-panels = 8MB on a 4MB L2 -> thrash,
// 45MB refetch, all pipes <16% busy.)
// BNP: v-half blocks (n0>=NDIM) emit per-tile BN sums (s, ss).
template<int BM, int BN, int BK, bool A_BF16, bool BNP>
__global__ __launch_bounds__(256) void gemm_f(
    const unsigned short* __restrict__ Abf, const float* __restrict__ Af,
    const float* __restrict__ Bf, float* __restrict__ C,
    const float* __restrict__ bias, float* __restrict__ bnpart,
    int M, int N, int K)
{
    constexpr int WM = BM / 2, WN = BN / 2;
    constexpr int MI = WM / 16, NI = WN / 16;
    constexpr int CPR = BK / 8;              // 16B bf16 chunks per row
    constexpr int RA = (BM * BK) / 8 / 256;  // f32-A chunk rounds
    constexpr int GA = (BM * BK) / 2048;     // bf16-A gl_lds rounds
    constexpr int RB = (BN * BK) / 8 / 256;  // f32-B chunk rounds

    __shared__ unsigned short As[2][BM * BK];
    __shared__ unsigned short Bs[2][BN * BK];

    const int tid  = threadIdx.x;
    const int lane = tid & 63;
    const int wid  = tid >> 6;
    const int wr   = wid >> 1;
    const int wc   = wid & 1;
    const int m0   = blockIdx.x * BM;   // fast dim -> XCD = m-block
    const int n0   = blockIdx.y * BN;
    const int fr   = lane & 15;
    const int kq   = lane >> 4;

    f32x4 acc[MI][NI] = {};
    float4 rga[RA > 0 ? RA : 1][2], rgb[RB][2];

    auto load_A = [&](int bs, int k0) {
        if constexpr (A_BF16) {
#pragma unroll
            for (int r = 0; r < GA; r++) {
                const int e   = r * 2048 + tid * 8;
                const int row = e / BK;
                const int swz = ((((e & (BK - 1)) >> 3) ^ (row & 7)) << 3);
                gl_lds16(Abf + (size_t)(m0 + row) * K + k0 + swz, &As[bs][e]);
            }
        } else {
#pragma unroll
            for (int r = 0; r < RA; r++) {
                const int idx = r * 256 + tid;
                const int row = idx / CPR, cc = idx % CPR;
                const float4* g = (const float4*)(Af + (size_t)(m0 + row) * K
                                                  + k0 + cc * 8);
                rga[r][0] = g[0];
                rga[r][1] = g[1];
            }
        }
    };
    auto load_B = [&](int k0) {
#pragma unroll
        for (int r = 0; r < RB; r++) {
            const int idx = r * 256 + tid;
            const int row = idx / CPR, cc = idx % CPR;
            const float4* g = (const float4*)(Bf + (size_t)(n0 + row) * K
                                              + k0 + cc * 8);
            rgb[r][0] = g[0];
            rgb[r][1] = g[1];
        }
    };
    auto write_A = [&](int bs) {
        if constexpr (!A_BF16) {
#pragma unroll
            for (int r = 0; r < RA; r++) {
                const int idx = r * 256 + tid;
                const int row = idx / CPR, cc = idx % CPR;
                bf16x8 v;
                v[0] = (__bf16)rga[r][0].x; v[1] = (__bf16)rga[r][0].y;
                v[2] = (__bf16)rga[r][0].z; v[3] = (__bf16)rga[r][0].w;
                v[4] = (__bf16)rga[r][1].x; v[5] = (__bf16)rga[r][1].y;
                v[6] = (__bf16)rga[r][1].z; v[7] = (__bf16)rga[r][1].w;
                *(bf16x8*)&As[bs][row * BK + ((cc ^ (row & 7)) << 3)] = v;
            }
        }
    };
    auto write_B = [&](int bs) {
#pragma unroll
        for (int r = 0; r < RB; r++) {
            const int idx = r * 256 + tid;
            const int row = idx / CPR, cc = idx % CPR;
            bf16x8 v;
            v[0] = (__bf16)rgb[r][0].x; v[1] = (__bf16)rgb[r][0].y;
            v[2] = (__bf16)rgb[r][0].z; v[3] = (__bf16)rgb[r][0].w;
            v[4] = (__bf16)rgb[r][1].x; v[5] = (__bf16)rgb[r][1].y;
            v[6] = (__bf16)rgb[r][1].z; v[7] = (__bf16)rgb[r][1].w;
            *(bf16x8*)&Bs[bs][row * BK + ((cc ^ (row & 7)) << 3)] = v;
        }
    };
    auto compute = [&](int bs) {
#pragma unroll
        for (int kh = 0; kh < BK / 32; kh++) {
            const int kchunk = kh * 4 + kq;
            bf16x8 af[MI], bfv[NI];
#pragma unroll
            for (int i = 0; i < MI; i++) {
                const int row = wr * WM + i * 16 + fr;
                af[i] = *(const bf16x8*)&As[bs][row * BK
                        + ((kchunk ^ (row & 7)) << 3)];
            }
#pragma unroll
            for (int j = 0; j < NI; j++) {
                const int row = wc * WN + j * 16 + fr;
                bfv[j] = *(const bf16x8*)&Bs[bs][row * BK
                         + ((kchunk ^ (row & 7)) << 3)];
            }
#pragma unroll
            for (int i = 0; i < MI; i++)
#pragma unroll
                for (int j = 0; j < NI; j++)
                    acc[i][j] = __builtin_amdgcn_mfma_f32_16x16x32_bf16(
                        af[i], bfv[j], acc[i][j], 0, 0, 0);
        }
    };

    load_A(0, 0);
    load_B(0);
    write_A(0);
    write_B(0);
    __syncthreads();

    const int NT = K / BK;
    int cur = 0;
    for (int t = 0; t < NT - 1; t++) {
        load_A(cur ^ 1, (t + 1) * BK);   // issue early (A_BF16: gl_lds direct)
        load_B((t + 1) * BK);            // issue early
        compute(cur);                    // MFMA hides global latency
        write_A(cur ^ 1);                // waits loads, cvt, ds_write
        write_B(cur ^ 1);
        __syncthreads();
        cur ^= 1;
    }
    compute(cur);

    const int row0 = m0 + wr * WM + (kq << 2);
    const int col0 = n0 + wc * WN + fr;
#pragma unroll
    for (int j = 0; j < NI; j++) {
        const int cc = col0 + j * 16;
        const float badd = bias ? bias[cc] : 0.0f;
#pragma unroll
        for (int i = 0; i < MI; i++)
#pragma unroll
            for (int r = 0; r < 4; r++)
                C[(size_t)(row0 + i * 16 + r) * N + cc] = acc[i][j][r] + badd;
    }

    if (BNP && n0 >= NDIM) {
        float s = 0.f, ss = 0.f;
#pragma unroll
        for (int i = 0; i < MI; i++)
#pragma unroll
            for (int j = 0; j < NI; j++)
#pragma unroll
                for (int r = 0; r < 4; r++) {
                    const float v = acc[i][j][r];
                    s += v;
                    ss = fmaf(v, v, ss);
                }
#pragma unroll
        for (int off = 32; off; off >>= 1) {
            s  += __shfl_down(s, off);
            ss += __shfl_down(ss, off);
        }
        __shared__ float rs[4], rss[4];
        if (lane == 0) { rs[wid] = s; rss[wid] = ss; }
        __syncthreads();
        if (tid == 0)
            ((float2*)bnpart)[((n0 - NDIM) >> 6) * 8 + (m0 >> 6)] =
                make_float2(rs[0] + rs[1] + rs[2] + rs[3],
                            rss[0] + rss[1] + rss[2] + rss[3]);
    }
}

// ---------------- fused BN-final + outer-product + softmax + PV --------
// Single-pass no-max softmax (|logit| <~ 30 << 88: exp can't overflow;
// shift-invariance => same result). All 16 bias float4 in flight upfront.
// Lanes 0-15 reduce this head's 16 BN partials -> (scale, shift).
// one block per (b,h); thread pair (2c,2c+1) owns row c, 64 elems each.
__global__ __launch_bounds__(256) void attn_k(
    const float* __restrict__ qv, const float* __restrict__ kparam,
    const float* __restrict__ bias, const float* __restrict__ temperature,
    const float* __restrict__ bnpart, const float* __restrict__ gamma,
    const float* __restrict__ beta, unsigned short* __restrict__ aout)
{
    const int bh = blockIdx.x;
    const int b  = bh >> 4;
    const int h  = bh & 15;
    const int tid = threadIdx.x;

    __shared__ float ks[NCPH], vsr[NCPH], s2sh[2];
    if (tid < 32)
        ((float4*)ks)[tid] =
            ((const float4*)(kparam + (size_t)b * NDIM + h * NCPH))[tid];
    else if (tid < 64)
        ((float4*)vsr)[tid - 32] =
            ((const float4*)(qv + (size_t)b * (2 * NDIM) + NDIM + h * NCPH))[tid - 32];

    if (tid < 16) {   // BN finalize: 16 partials for this head
        float2 p = ((const float2*)bnpart)[(h * 2 + (tid >> 3)) * 8 + (tid & 7)];
        float s = p.x, ss = p.y;
#pragma unroll
        for (int off = 8; off; off >>= 1) {
            s  += __shfl_xor(s, off);
            ss += __shfl_xor(ss, off);
        }
        if (tid == 0) {
            const float inv = 1.0f / (NBATCH * NCPH);
            float mean = s * inv;
            float var  = ss * inv - mean * mean;
            float sc   = gamma[h] * rsqrtf(var + 1e-5f);
            s2sh[0] = sc;
            s2sh[1] = beta[h] - mean * sc;
        }
    }

    const int c = tid >> 1, half = tid & 1;
    const float qc   = qv[(size_t)b * (2 * NDIM) + h * NCPH + c];
    const float temp = temperature[h];

    // all 64 bias values in flight before any dependent compute
    const float4* bp = (const float4*)(bias + ((size_t)bh << 14)
                                       + (size_t)c * NCPH + half * 64);
    float4 l4[16];
#pragma unroll
    for (int j = 0; j < 16; j++) l4[j] = bp[j];

    __syncthreads();
    const float sc = s2sh[0], sh = s2sh[1];
    const float4* kk4 = (const float4*)(ks  + half * 64);
    const float4* vv4 = (const float4*)(vsr + half * 64);

    float s0 = 0.f, s1 = 0.f, o0 = 0.f, o1 = 0.f;
#pragma unroll
    for (int j = 0; j < 16; j++) {
        const float4 bb = l4[j];
        const float4 kx = kk4[j];
        const float4 vx = vv4[j];
        float px = __expf(fmaf(qc, kx.x, bb.x) * temp);
        float py = __expf(fmaf(qc, kx.y, bb.y) * temp);
        float pz = __expf(fmaf(qc, kx.z, bb.z) * temp);
        float pw = __expf(fmaf(qc, kx.w, bb.w) * temp);
        s0 += px; s1 += py; s0 += pz; s1 += pw;
        o0 = fmaf(px, vx.x, o0);
        o1 = fmaf(py, vx.y, o1);
        o0 = fmaf(pz, vx.z, o0);
        o1 = fmaf(pw, vx.w, o1);
    }
    float s = s0 + s1, o = o0 + o1;
    s += __shfl_xor(s, 1);
    o += __shfl_xor(o, 1);

    if (half == 0)
        aout[(size_t)b * NDIM + h * NCPH + c] = f2bf(fmaf(sc, o / s, sh));
}

// ------------------------------ launch ---------------------------------
extern "C" void kernel_launch(void* const* d_in, const int* in_sizes, int n_in,
                              void* d_out, int out_size, void* d_ws, size_t ws_size,
                              hipStream_t stream)
{
    const float* x      = (const float*)d_in[0];
    const float* Wqv    = (const float*)d_in[1];
    const float* temp   = (const float*)d_in[2];
    const float* kparam = (const float*)d_in[3];
    const float* bias   = (const float*)d_in[4];
    const float* gamma  = (const float*)d_in[5];
    const float* beta   = (const float*)d_in[6];
    const float* Wout   = (const float*)d_in[7];
    const float* bout   = (const float*)d_in[8];
    float* out = (float*)d_out;

    char* ws = (char*)d_ws;
    float*          qv     = (float*)(ws);                      // 8 MiB
    unsigned short* ao_bf  = (unsigned short*)(ws + 8388608);   // 2 MiB
    float*          bnpart = (float*)(ws + 10485760);           // 2 KiB

    // qv = x @ W_qv^T : M=512, N=4096, K=2048
    // grid (m-blocks=8, n-blocks=64): XCD = id%8 = m-block -> A-panel hot
    gemm_f<64, 64, 64, false, true><<<dim3(8, 64), 256, 0, stream>>>(
        nullptr, x, Wqv, qv, nullptr, bnpart, NBATCH, 2 * NDIM, NDIM);

    attn_k<<<NBATCH * NHEADS, 256, 0, stream>>>(
        qv, kparam, bias, temp, bnpart, gamma, beta, ao_bf);

    // out = attn_out @ W_out^T + b_out : M=512, N=2048, K=2048
    gemm_f<64, 32, 64, true, false><<<dim3(8, 64), 256, 0, stream>>>(
        ao_bf, nullptr, Wout, out, bout, nullptr, NBATCH, NDIM, NDIM);
}